// Round 9
// baseline (328.734 us; speedup 1.0000x reference)
//
#include <hip/hip_runtime.h>

#define TT 512   // max sequence length T
#define NN 128   // number of tags N
#define NTHR 256 // FAST kernel: 4 waves = 1 wave per SIMD
#define FTHR 512 // fallback kernel thread count
#define SROW 160 // swizzled state row: 8 chunks x 20 floats (16 used + 4 pad)
#define SW(i) (20 * ((i) >> 4) + ((i) & 15))
#define TTS 130  // tt (T^T) row stride in floats: bank step 2, float2-aligned
#define BD  64   // (fallback kernel) backtrack chunk depth
#define MAXG 8   // (fallback kernel)

// Barrier WITHOUT vmcnt drain: LDS writes drained, global loads/stores stay
// in flight across the barrier.
#define STEP_BARRIER() asm volatile("s_waitcnt lgkmcnt(0)\n\ts_barrier" ::: "memory")

typedef float v2f __attribute__((ext_vector_type(2)));
__device__ __forceinline__ v2f vmax2(v2f a, v2f b) {
    v2f r; r.x = fmaxf(a.x, b.x); r.y = fmaxf(a.y, b.y); return r;
}

// DPP cross-lane (pure VALU, no LDS pipe)
template <int CTRL>
__device__ __forceinline__ int dpp_i(int x) {
    return __builtin_amdgcn_update_dpp(x, x, CTRL, 0xf, 0xf, true);
}
template <int CTRL>
__device__ __forceinline__ float dpp_f(float x) {
    union { float f; int i; } u; u.f = x;
    u.i = dpp_i<CTRL>(u.i);
    return u.f;
}
#define DPP_XOR1 0xB1   // quad_perm [1,0,3,2] : lane ^= 1
#define DPP_XOR2 0x4E   // quad_perm [2,3,0,1] : lane ^= 2
#define DPP_MIR7 0x141  // row_half_mirror (lane^=7): == ^4 after 1,2 (fallback)

// R18: exact revert to R3 (champion, 239us best-dispatch) with ONE safe
// rebalance: after the DPP merge all 4 quad lanes hold both bv values, so
// the ws global store moves to lanes c=2,3 (c=2: tag j, c=3: tag j+64).
// Lanes c=0,1 now only do the LDS state write before the barrier -> shorter
// pre-barrier tail on the lanes the recursion waits on. Same values, same
// addresses, different lanes -> correctness unchanged by construction.
// Chase is R3's exact two-ballot form (R17's "shortened" chase regressed).
__global__ __launch_bounds__(NTHR, 1)
void crf_viterbi_fast(const float* __restrict__ logits,
                      const float* __restrict__ trans,
                      const int* __restrict__ seqlen,
                      int* __restrict__ out,
                      float* __restrict__ ws) {
    __shared__ float stateBuf[2][SROW];
    __shared__ float tt[NN * TTS];  // tt[j*TTS+i] = trans[i*NN+j]
    __shared__ float redV[NN];
    __shared__ int   redI[NN];
    __shared__ int   tagBuf[TT];

    const int tid = threadIdx.x;
    const int j   = tid >> 2;   // 0..63 (serves tags j and j+64)
    const int c   = tid & 3;    // i-chunk (32 i's each)
    const int i0  = c << 5;
    const int b   = blockIdx.x;
    const int L   = seqlen[b];  // in [1, TT]
    const int lm1 = L - 1;
    const int jx  = j + ((c & 1) << 6);

    const float* lrow = logits + (size_t)b * TT * NN;
    float* wsb = ws + (size_t)b * TT * NN;

    // 4-deep logits prefetch ring
    auto xl = [&](int r) -> float {
        r = (r < lm1) ? r : lm1;
        return lrow[r * NN + jx];
    };
    float X0 = xl(1), X1 = xl(2), X2 = xl(3), X3 = xl(4);

    // Transition chunks in registers, packed for v_pk_add_f32 / v_pk_max_f32
    v2f tr0[16], tr1[16];
    #pragma unroll
    for (int p = 0; p < 16; ++p) {
        tr0[p].x = trans[(i0 + 2 * p)     * NN + j];
        tr0[p].y = trans[(i0 + 2 * p + 1) * NN + j];
        tr1[p].x = trans[(i0 + 2 * p)     * NN + j + 64];
        tr1[p].y = trans[(i0 + 2 * p + 1) * NN + j + 64];
    }

    // Transposed copy for backtrack. Stride TTS=130: write bank step 2,
    // reads float2-aligned.
    for (int k = 0; k < (NN * NN) / NTHR; ++k) {
        int idx = k * NTHR + tid;
        tt[(idx & 127) * TTS + (idx >> 7)] = trans[idx];
    }

    if (c < 2) {   // t = 0 init: LDS state = x[0]; ws row 0 = 0 (M[0] := 0)
        stateBuf[0][SW(jx)] = lrow[jx];
        wsb[jx] = 0.0f;
    }
    __syncthreads();

    // 32-candidate packed add+max tree; value-only, order-invariant -> exact.
    #define REDUCE32(TR, OUT)                                                  \
    {                                                                          \
        v2f m0 = vmax2(sv0 + TR[0],  sv1 + TR[1]);                             \
        v2f m1 = vmax2(sv2 + TR[2],  sv3 + TR[3]);                             \
        v2f m2 = vmax2(sv4 + TR[4],  sv5 + TR[5]);                             \
        v2f m3 = vmax2(sv6 + TR[6],  sv7 + TR[7]);                             \
        v2f m4 = vmax2(sv8 + TR[8],  sv9 + TR[9]);                             \
        v2f m5 = vmax2(sv10 + TR[10], sv11 + TR[11]);                          \
        v2f m6 = vmax2(sv12 + TR[12], sv13 + TR[13]);                          \
        v2f m7 = vmax2(sv14 + TR[14], sv15 + TR[15]);                          \
        m0 = vmax2(m0, m1); m2 = vmax2(m2, m3);                                \
        m4 = vmax2(m4, m5); m6 = vmax2(m6, m7);                                \
        m0 = vmax2(m0, m2); m4 = vmax2(m4, m6);                                \
        m0 = vmax2(m0, m4);                                                    \
        OUT = fmaxf(m0.x, m0.y);                                               \
    }

    auto vstep = [&](const float* st, float* dst, int t, float& xslot) {
        float xa_use = xslot;          // x[t], loaded 4 steps ago
        int tn = t + 4;                // refill ring slot with x[t+4]
        tn = (tn < lm1) ? tn : lm1;
        xslot = lrow[tn * NN + jx];

        // two 20-float chunks (chunks 2c and 2c+1 of the swizzled row)
        const float* sp = st + 40 * c;
        float4 a0 = *(const float4*)(sp);
        float4 a1 = *(const float4*)(sp + 4);
        float4 a2 = *(const float4*)(sp + 8);
        float4 a3 = *(const float4*)(sp + 12);
        float4 a4 = *(const float4*)(sp + 20);
        float4 a5 = *(const float4*)(sp + 24);
        float4 a6 = *(const float4*)(sp + 28);
        float4 a7 = *(const float4*)(sp + 32);

        v2f sv0  = {a0.x, a0.y}, sv1  = {a0.z, a0.w};
        v2f sv2  = {a1.x, a1.y}, sv3  = {a1.z, a1.w};
        v2f sv4  = {a2.x, a2.y}, sv5  = {a2.z, a2.w};
        v2f sv6  = {a3.x, a3.y}, sv7  = {a3.z, a3.w};
        v2f sv8  = {a4.x, a4.y}, sv9  = {a4.z, a4.w};
        v2f sv10 = {a5.x, a5.y}, sv11 = {a5.z, a5.w};
        v2f sv12 = {a6.x, a6.y}, sv13 = {a6.z, a6.w};
        v2f sv14 = {a7.x, a7.y}, sv15 = {a7.z, a7.w};

        float bv0, bv1;
        REDUCE32(tr0, bv0)
        REDUCE32(tr1, bv1)

        // value-only quad merge (c = 0..3): all 4 lanes get both full maxes
        bv0 = fmaxf(bv0, dpp_f<DPP_XOR1>(bv0)); bv1 = fmaxf(bv1, dpp_f<DPP_XOR1>(bv1));
        bv0 = fmaxf(bv0, dpp_f<DPP_XOR2>(bv0)); bv1 = fmaxf(bv1, dpp_f<DPP_XOR2>(bv1));

        // rebalanced writes: c=0,1 -> LDS state (critical); c=2,3 -> ws (off-chain)
        if (c < 2) {
            float bv = c ? bv1 : bv0;
            dst[SW(jx)] = bv + xa_use;          // next step's state S[t]
        } else {
            float bv = (c & 1) ? bv1 : bv0;
            wsb[t * NN + jx] = bv;              // pre-logit max M[t] (backtrack)
        }
        STEP_BARRIER();   // lgkm-only: global loads/stores stay in flight
    };
    #undef REDUCE32

    int t = 1;
    for (; t + 4 < L; t += 4) {
        vstep(stateBuf[0], stateBuf[1], t,     X0);
        vstep(stateBuf[1], stateBuf[0], t + 1, X1);
        vstep(stateBuf[0], stateBuf[1], t + 2, X2);
        vstep(stateBuf[1], stateBuf[0], t + 3, X3);
    }
    if (t     < L) vstep(stateBuf[0], stateBuf[1], t,     X0);
    if (t + 1 < L) vstep(stateBuf[1], stateBuf[0], t + 1, X1);
    if (t + 2 < L) vstep(stateBuf[0], stateBuf[1], t + 2, X2);
    if (t + 3 < L) vstep(stateBuf[1], stateBuf[0], t + 3, X3);

    __syncthreads();   // full drain: ws stores complete & visible
    const int pf = (L - 1) & 1;

    // Final argmax over state (first-occurrence: min index on ties).
    if (tid < NN) { redV[tid] = stateBuf[pf][SW(tid)]; redI[tid] = tid; }
    __syncthreads();
    #pragma unroll
    for (int off = 64; off >= 1; off >>= 1) {
        if (tid < off) {
            float va = redV[tid], vb = redV[tid + off];
            int   ia = redI[tid], ib = redI[tid + off];
            if (vb > va || (vb == va && ib < ia)) { redV[tid] = vb; redI[tid] = ib; }
        }
        __syncthreads();
    }

    // ---- Backtrack: wave 0, equality-ballot chase (R3 exact form) ----
    if (tid < 64) {
        const int lane = tid;
        int jc = redI[0];
        if (lane == 0) tagBuf[L - 1] = jc;

        auto wrow = [&](int r) -> float2 {   // M row (clamped; clamped rows unused)
            r = (r < 0) ? 0 : r;
            return *(const float2*)(wsb + r * NN + 2 * lane);
        };
        auto xrow = [&](int r) -> float2 {   // logits row
            r = (r < 0) ? 0 : r;
            return *(const float2*)(lrow + r * NN + 2 * lane);
        };
        auto extract2 = [&](float2 v, int idx) -> float {  // v[idx], idx uniform
            int sel = idx >> 1;
            int wx = __builtin_amdgcn_readlane(__float_as_int(v.x), sel);
            int wy = __builtin_amdgcn_readlane(__float_as_int(v.y), sel);
            return __int_as_float((idx & 1) ? wy : wx);
        };

        float target;
        {
            float2 rT = wrow(L - 1);
            target = extract2(rT, jc);       // M[L-1][jc]
        }

        // chase step t: uses m = M[t-1] row, xr = x[t-1] row.
        // bp = first i with (m[i]+xr[i])+T[i][jc] == target (bitwise-exact
        // recompute of forward candidates -> exact first-occurrence argmax).
        auto chase = [&](float2 m, float2 xr, int tc) {
            float2 tp = *(const float2*)(tt + jc * TTS + 2 * lane);
            float cA = (m.x + xr.x) + tp.x;
            float cB = (m.y + xr.y) + tp.y;
            unsigned long long mA = __ballot(cA == target);
            unsigned long long mB = __ballot(cB == target);
            int iA = mA ? (2 * (__ffsll(mA) - 1))     : (1 << 30);
            int iB = mB ? (2 * (__ffsll(mB) - 1) + 1) : (1 << 30);
            int bp = (iA < iB) ? iA : iB;
            if (lane == 0) tagBuf[tc - 1] = bp;
            target = extract2(m, bp);        // M[t-1][bp] for the next step
            jc = bp;
        };

        // 8-deep prefetch ring, statically unrolled
        float2 m0 = wrow(L - 2), x0 = xrow(L - 2);
        float2 m1 = wrow(L - 3), x1 = xrow(L - 3);
        float2 m2 = wrow(L - 4), x2 = xrow(L - 4);
        float2 m3 = wrow(L - 5), x3 = xrow(L - 5);
        float2 m4 = wrow(L - 6), x4 = xrow(L - 6);
        float2 m5 = wrow(L - 7), x5 = xrow(L - 7);
        float2 m6 = wrow(L - 8), x6 = xrow(L - 8);
        float2 m7 = wrow(L - 9), x7 = xrow(L - 9);
        int tb = L - 1;
        while (tb >= 8) {
            chase(m0, x0, tb);     m0 = wrow(tb - 9);  x0 = xrow(tb - 9);
            chase(m1, x1, tb - 1); m1 = wrow(tb - 10); x1 = xrow(tb - 10);
            chase(m2, x2, tb - 2); m2 = wrow(tb - 11); x2 = xrow(tb - 11);
            chase(m3, x3, tb - 3); m3 = wrow(tb - 12); x3 = xrow(tb - 12);
            chase(m4, x4, tb - 4); m4 = wrow(tb - 13); x4 = xrow(tb - 13);
            chase(m5, x5, tb - 5); m5 = wrow(tb - 14); x5 = xrow(tb - 14);
            chase(m6, x6, tb - 6); m6 = wrow(tb - 15); x6 = xrow(tb - 15);
            chase(m7, x7, tb - 7); m7 = wrow(tb - 16); x7 = xrow(tb - 16);
            tb -= 8;
        }
        if (tb >= 1) chase(m0, x0, tb);
        if (tb >= 2) chase(m1, x1, tb - 1);
        if (tb >= 3) chase(m2, x2, tb - 2);
        if (tb >= 4) chase(m3, x3, tb - 3);
        if (tb >= 5) chase(m4, x4, tb - 4);
        if (tb >= 6) chase(m5, x5, tb - 5);
        if (tb >= 7) chase(m6, x6, tb - 6);
    }
    __syncthreads();

    // Coalesced output: tags for k < L, zeros for the masked tail.
    out[(size_t)b * TT + tid]       = (tid < L)       ? tagBuf[tid]       : 0;
    out[(size_t)b * TT + tid + 256] = (tid + 256 < L) ? tagBuf[tid + 256] : 0;
}

// ---------------- FALLBACK kernel: R5 (proven), used if ws too small --------
__global__ __launch_bounds__(FTHR, 1)
void crf_viterbi_fallback(const float* __restrict__ logits,
                          const float* __restrict__ trans,
                          const int* __restrict__ seqlen,
                          int* __restrict__ out) {
    __shared__ float stateBuf[2][SROW];
    __shared__ float redV[NN];
    __shared__ int   redI[NN];
    __shared__ int   tagBuf[TT];
    __shared__ int   entryTag[MAXG];
    __shared__ unsigned char bp[TT][NN];
    __shared__ unsigned char hist[MAXG][BD][NN];

    const int tid = threadIdx.x;
    const int j   = tid >> 3;
    const int c   = tid & 7;
    const int i0  = c << 4;
    const int b   = blockIdx.x;
    const int L   = seqlen[b];

    float tr0[16], tr1[16];
    #pragma unroll
    for (int k = 0; k < 16; ++k) {
        tr0[k] = trans[(i0 + k) * NN + j];
        tr1[k] = trans[(i0 + k) * NN + j + 64];
    }

    const float* lrow = logits + (size_t)b * TT * NN;
    if (c < 2) {
        int jj = j + (c << 6);
        stateBuf[0][SW(jj)] = lrow[jj];
    }
    __syncthreads();

    float xa0 = lrow[NN + j], xa1 = lrow[NN + j + 64];
    int p = 0;
    for (int t = 1; t < L; ++t) {
        int tn = (t + 1 < L) ? (t + 1) : (L - 1);
        const float* lp = lrow + tn * NN;
        float xb0 = lp[j];
        float xb1 = lp[j + 64];

        const float* st = stateBuf[p] + 20 * c;
        float4 a0 = *(const float4*)(st);
        float4 a1 = *(const float4*)(st + 4);
        float4 a2 = *(const float4*)(st + 8);
        float4 a3 = *(const float4*)(st + 12);

        float best0 = -__builtin_inff(), best1 = -__builtin_inff();
        int arg0 = 0, arg1 = 0;
        #define ELEM(S, K)                                                  \
        {                                                                   \
            float sc = (S) + tr0[K];                                        \
            bool g = sc > best0; best0 = g ? sc : best0; arg0 = g ? (K) : arg0; \
            float sd = (S) + tr1[K];                                        \
            bool h = sd > best1; best1 = h ? sd : best1; arg1 = h ? (K) : arg1; \
        }
        ELEM(a0.x, 0)  ELEM(a0.y, 1)  ELEM(a0.z, 2)  ELEM(a0.w, 3)
        ELEM(a1.x, 4)  ELEM(a1.y, 5)  ELEM(a1.z, 6)  ELEM(a1.w, 7)
        ELEM(a2.x, 8)  ELEM(a2.y, 9)  ELEM(a2.z, 10) ELEM(a2.w, 11)
        ELEM(a3.x, 12) ELEM(a3.y, 13) ELEM(a3.z, 14) ELEM(a3.w, 15)
        #undef ELEM

        float bv0 = best0, bv1 = best1;
        int   bi0 = i0 + arg0, bi1 = i0 + arg1;
        #define MERGE_STAGE(CTRL, LOWER)                                   \
        {                                                                  \
            float p0 = dpp_f<CTRL>(bv0); int q0 = dpp_i<CTRL>(bi0);        \
            float p1 = dpp_f<CTRL>(bv1); int q1 = dpp_i<CTRL>(bi1);        \
            bool lower = (LOWER);                                          \
            bool t0 = (p0 > bv0) || (p0 == bv0 && lower);                  \
            bool t1 = (p1 > bv1) || (p1 == bv1 && lower);                  \
            bv0 = t0 ? p0 : bv0; bi0 = t0 ? q0 : bi0;                      \
            bv1 = t1 ? p1 : bv1; bi1 = t1 ? q1 : bi1;                      \
        }
        MERGE_STAGE(DPP_XOR1, (c & 1) != 0)
        MERGE_STAGE(DPP_XOR2, (c & 2) != 0)
        MERGE_STAGE(DPP_MIR7, (c & 4) != 0)
        #undef MERGE_STAGE

        if (c < 2) {
            int   jj = j + (c << 6);
            float bv = c ? bv1 : bv0;
            int   bi = c ? bi1 : bi0;
            float xx = c ? xa1 : xa0;
            stateBuf[p ^ 1][SW(jj)] = bv + xx;
            bp[t][jj] = (unsigned char)bi;
        }
        xa0 = xb0; xa1 = xb1;
        __syncthreads();
        p ^= 1;
    }

    if (tid < NN) { redV[tid] = stateBuf[p][SW(tid)]; redI[tid] = tid; }
    __syncthreads();
    #pragma unroll
    for (int off = 64; off >= 1; off >>= 1) {
        if (tid < off) {
            float va = redV[tid], vb = redV[tid + off];
            int   ia = redI[tid], ib = redI[tid + off];
            if (vb > va || (vb == va && ib < ia)) { redV[tid] = vb; redI[tid] = ib; }
        }
        __syncthreads();
    }

    const int M = L - 1;
    const int G = (M + BD - 1) / BD;
    {
        int s  = tid & 127;
        int gA = tid >> 7;
        int gB = gA + 4;
        int thA = M - gA * BD, thB = M - gB * BD;
        int dA  = (gA < G) ? ((thA < BD) ? thA : BD) : 0;
        int dB  = (gB < G) ? ((thB < BD) ? thB : BD) : 0;
        int curA = s, curB = s;
        int maxd = (dA > dB) ? dA : dB;
        for (int d = 0; d < maxd; ++d) {
            if (d < dA) { curA = bp[thA - d][curA]; hist[gA][d][s] = (unsigned char)curA; }
            if (d < dB) { curB = bp[thB - d][curB]; hist[gB][d][s] = (unsigned char)curB; }
        }
    }
    __syncthreads();
    if (tid == 0) {
        int e = redI[0];
        tagBuf[L - 1] = e;
        for (int g = 0; g < G; ++g) {
            entryTag[g] = e;
            if (g + 1 < G) e = hist[g][BD - 1][e];
        }
    }
    __syncthreads();
    {
        int g = tid >> 6, d = tid & 63;
        if (g < MAXG && g < G) {
            int th  = M - g * BD;
            int dep = (th < BD) ? th : BD;
            if (d < dep) {
                int e = entryTag[g];
                tagBuf[th - 1 - d] = hist[g][d][e];
            }
        }
    }
    __syncthreads();
    out[(size_t)b * TT + tid] = (tid < L) ? tagBuf[tid] : 0;
}

extern "C" void kernel_launch(void* const* d_in, const int* in_sizes, int n_in,
                              void* d_out, int out_size, void* d_ws, size_t ws_size,
                              hipStream_t stream) {
    const float* logits = (const float*)d_in[0];
    const float* trans  = (const float*)d_in[1];
    const int*   seqlen = (const int*)d_in[2];
    int*         out    = (int*)d_out;
    const int B = in_sizes[2];  // 256
    const size_t need = (size_t)B * TT * NN * sizeof(float);  // 64 MiB
    if (ws_size >= need) {
        crf_viterbi_fast<<<B, NTHR, 0, stream>>>(logits, trans, seqlen, out,
                                                 (float*)d_ws);
    } else {
        crf_viterbi_fallback<<<B, FTHR, 0, stream>>>(logits, trans, seqlen, out);
    }
}

// Round 10
// 311.881 us; speedup vs baseline: 1.0540x; 1.0540x over previous
//
#include <hip/hip_runtime.h>

#define TT 512   // max sequence length T
#define NN 128   // number of tags N
#define NTHR 256 // FAST kernel: 4 waves = 1 wave per SIMD
#define FTHR 512 // fallback kernel thread count
#define SROW 160 // swizzled state row: 8 chunks x 20 floats (16 used + 4 pad)
#define SW(i) (20 * ((i) >> 4) + ((i) & 15))
#define TTS 130  // tt (T^T) row stride in floats: bank step 2, float2-aligned
#define BD  64   // (fallback kernel) backtrack chunk depth
#define MAXG 8   // (fallback kernel)

// Barrier WITHOUT vmcnt drain: LDS writes drained, global loads/stores stay
// in flight across the barrier.
#define STEP_BARRIER() asm volatile("s_waitcnt lgkmcnt(0)\n\ts_barrier" ::: "memory")

typedef float v2f __attribute__((ext_vector_type(2)));
__device__ __forceinline__ v2f vmax2(v2f a, v2f b) {
    v2f r; r.x = fmaxf(a.x, b.x); r.y = fmaxf(a.y, b.y); return r;
}

// DPP cross-lane (pure VALU, no LDS pipe)
template <int CTRL>
__device__ __forceinline__ int dpp_i(int x) {
    return __builtin_amdgcn_update_dpp(x, x, CTRL, 0xf, 0xf, true);
}
template <int CTRL>
__device__ __forceinline__ float dpp_f(float x) {
    union { float f; int i; } u; u.f = x;
    u.i = dpp_i<CTRL>(u.i);
    return u.f;
}
#define DPP_XOR1 0xB1   // quad_perm [1,0,3,2] : lane ^= 1
#define DPP_XOR2 0x4E   // quad_perm [2,3,0,1] : lane ^= 2
#define DPP_MIR7 0x141  // row_half_mirror (lane^=7): == ^4 after 1,2 (fallback)

// R19: byte-exact restore of the R3 champion (239us best-dispatch, 312.7us
// bench; absmax 0). Nine rounds of structural experiments all regressed:
// in-forward bp extraction x3 (VCC hazards / register liveness), wave
// specialization (wave-serial ballots), DS-pipe thinning, chase shortening,
// write rebalance. The kernel is latency-bound on the serial Viterbi
// recursion (HBM 4%, VALU 19%): step-pair ~1127cy = forward ~700 (LDS
// round-trip + barrier + in-order issue) + chase ~427 (jc-dependent LDS read
// + ballot round-trips). This source is the measured structural floor.
__global__ __launch_bounds__(NTHR, 1)
void crf_viterbi_fast(const float* __restrict__ logits,
                      const float* __restrict__ trans,
                      const int* __restrict__ seqlen,
                      int* __restrict__ out,
                      float* __restrict__ ws) {
    __shared__ float stateBuf[2][SROW];
    __shared__ float tt[NN * TTS];  // tt[j*TTS+i] = trans[i*NN+j]
    __shared__ float redV[NN];
    __shared__ int   redI[NN];
    __shared__ int   tagBuf[TT];

    const int tid = threadIdx.x;
    const int j   = tid >> 2;   // 0..63 (serves tags j and j+64)
    const int c   = tid & 3;    // i-chunk (32 i's each)
    const int i0  = c << 5;
    const int b   = blockIdx.x;
    const int L   = seqlen[b];  // in [1, TT]
    const int lm1 = L - 1;
    const int jx  = j + ((c & 1) << 6);

    const float* lrow = logits + (size_t)b * TT * NN;
    float* wsb = ws + (size_t)b * TT * NN;

    // 4-deep logits prefetch ring
    auto xl = [&](int r) -> float {
        r = (r < lm1) ? r : lm1;
        return lrow[r * NN + jx];
    };
    float X0 = xl(1), X1 = xl(2), X2 = xl(3), X3 = xl(4);

    // Transition chunks in registers, packed for v_pk_add_f32 / v_pk_max_f32
    v2f tr0[16], tr1[16];
    #pragma unroll
    for (int p = 0; p < 16; ++p) {
        tr0[p].x = trans[(i0 + 2 * p)     * NN + j];
        tr0[p].y = trans[(i0 + 2 * p + 1) * NN + j];
        tr1[p].x = trans[(i0 + 2 * p)     * NN + j + 64];
        tr1[p].y = trans[(i0 + 2 * p + 1) * NN + j + 64];
    }

    // Transposed copy for backtrack. Stride TTS=130: write bank step 2,
    // reads float2-aligned.
    for (int k = 0; k < (NN * NN) / NTHR; ++k) {
        int idx = k * NTHR + tid;
        tt[(idx & 127) * TTS + (idx >> 7)] = trans[idx];
    }

    if (c < 2) {   // t = 0 init: LDS state = x[0]; ws row 0 = 0 (M[0] := 0)
        stateBuf[0][SW(jx)] = lrow[jx];
        wsb[jx] = 0.0f;
    }
    __syncthreads();

    // 32-candidate packed add+max tree; value-only, order-invariant -> exact.
    #define REDUCE32(TR, OUT)                                                  \
    {                                                                          \
        v2f m0 = vmax2(sv0 + TR[0],  sv1 + TR[1]);                             \
        v2f m1 = vmax2(sv2 + TR[2],  sv3 + TR[3]);                             \
        v2f m2 = vmax2(sv4 + TR[4],  sv5 + TR[5]);                             \
        v2f m3 = vmax2(sv6 + TR[6],  sv7 + TR[7]);                             \
        v2f m4 = vmax2(sv8 + TR[8],  sv9 + TR[9]);                             \
        v2f m5 = vmax2(sv10 + TR[10], sv11 + TR[11]);                          \
        v2f m6 = vmax2(sv12 + TR[12], sv13 + TR[13]);                          \
        v2f m7 = vmax2(sv14 + TR[14], sv15 + TR[15]);                          \
        m0 = vmax2(m0, m1); m2 = vmax2(m2, m3);                                \
        m4 = vmax2(m4, m5); m6 = vmax2(m6, m7);                                \
        m0 = vmax2(m0, m2); m4 = vmax2(m4, m6);                                \
        m0 = vmax2(m0, m4);                                                    \
        OUT = fmaxf(m0.x, m0.y);                                               \
    }

    auto vstep = [&](const float* st, float* dst, int t, float& xslot) {
        float xa_use = xslot;          // x[t], loaded 4 steps ago
        int tn = t + 4;                // refill ring slot with x[t+4]
        tn = (tn < lm1) ? tn : lm1;
        xslot = lrow[tn * NN + jx];

        // two 20-float chunks (chunks 2c and 2c+1 of the swizzled row)
        const float* sp = st + 40 * c;
        float4 a0 = *(const float4*)(sp);
        float4 a1 = *(const float4*)(sp + 4);
        float4 a2 = *(const float4*)(sp + 8);
        float4 a3 = *(const float4*)(sp + 12);
        float4 a4 = *(const float4*)(sp + 20);
        float4 a5 = *(const float4*)(sp + 24);
        float4 a6 = *(const float4*)(sp + 28);
        float4 a7 = *(const float4*)(sp + 32);

        v2f sv0  = {a0.x, a0.y}, sv1  = {a0.z, a0.w};
        v2f sv2  = {a1.x, a1.y}, sv3  = {a1.z, a1.w};
        v2f sv4  = {a2.x, a2.y}, sv5  = {a2.z, a2.w};
        v2f sv6  = {a3.x, a3.y}, sv7  = {a3.z, a3.w};
        v2f sv8  = {a4.x, a4.y}, sv9  = {a4.z, a4.w};
        v2f sv10 = {a5.x, a5.y}, sv11 = {a5.z, a5.w};
        v2f sv12 = {a6.x, a6.y}, sv13 = {a6.z, a6.w};
        v2f sv14 = {a7.x, a7.y}, sv15 = {a7.z, a7.w};

        float bv0, bv1;
        REDUCE32(tr0, bv0)
        REDUCE32(tr1, bv1)

        // value-only quad merge (c = 0..3)
        bv0 = fmaxf(bv0, dpp_f<DPP_XOR1>(bv0)); bv1 = fmaxf(bv1, dpp_f<DPP_XOR1>(bv1));
        bv0 = fmaxf(bv0, dpp_f<DPP_XOR2>(bv0)); bv1 = fmaxf(bv1, dpp_f<DPP_XOR2>(bv1));

        if (c < 2) {
            float bv = c ? bv1 : bv0;
            dst[SW(jx)] = bv + xa_use; // next step's state S[t]
            wsb[t * NN + jx] = bv;     // pre-logit max M[t] (for backtrack)
        }
        STEP_BARRIER();   // lgkm-only: global loads/stores stay in flight
    };
    #undef REDUCE32

    int t = 1;
    for (; t + 4 < L; t += 4) {
        vstep(stateBuf[0], stateBuf[1], t,     X0);
        vstep(stateBuf[1], stateBuf[0], t + 1, X1);
        vstep(stateBuf[0], stateBuf[1], t + 2, X2);
        vstep(stateBuf[1], stateBuf[0], t + 3, X3);
    }
    if (t     < L) vstep(stateBuf[0], stateBuf[1], t,     X0);
    if (t + 1 < L) vstep(stateBuf[1], stateBuf[0], t + 1, X1);
    if (t + 2 < L) vstep(stateBuf[0], stateBuf[1], t + 2, X2);
    if (t + 3 < L) vstep(stateBuf[1], stateBuf[0], t + 3, X3);

    __syncthreads();   // full drain: ws stores complete & visible
    const int pf = (L - 1) & 1;

    // Final argmax over state (first-occurrence: min index on ties).
    if (tid < NN) { redV[tid] = stateBuf[pf][SW(tid)]; redI[tid] = tid; }
    __syncthreads();
    #pragma unroll
    for (int off = 64; off >= 1; off >>= 1) {
        if (tid < off) {
            float va = redV[tid], vb = redV[tid + off];
            int   ia = redI[tid], ib = redI[tid + off];
            if (vb > va || (vb == va && ib < ia)) { redV[tid] = vb; redI[tid] = ib; }
        }
        __syncthreads();
    }

    // ---- Backtrack: wave 0, equality-ballot chase ----
    if (tid < 64) {
        const int lane = tid;
        int jc = redI[0];
        if (lane == 0) tagBuf[L - 1] = jc;

        auto wrow = [&](int r) -> float2 {   // M row (clamped; clamped rows unused)
            r = (r < 0) ? 0 : r;
            return *(const float2*)(wsb + r * NN + 2 * lane);
        };
        auto xrow = [&](int r) -> float2 {   // logits row
            r = (r < 0) ? 0 : r;
            return *(const float2*)(lrow + r * NN + 2 * lane);
        };
        auto extract2 = [&](float2 v, int idx) -> float {  // v[idx], idx uniform
            int sel = idx >> 1;
            int wx = __builtin_amdgcn_readlane(__float_as_int(v.x), sel);
            int wy = __builtin_amdgcn_readlane(__float_as_int(v.y), sel);
            return __int_as_float((idx & 1) ? wy : wx);
        };

        float target;
        {
            float2 rT = wrow(L - 1);
            target = extract2(rT, jc);       // M[L-1][jc]
        }

        // chase step t: uses m = M[t-1] row, xr = x[t-1] row.
        // bp = first i with (m[i]+xr[i])+T[i][jc] == target (bitwise-exact
        // recompute of forward candidates -> exact first-occurrence argmax).
        auto chase = [&](float2 m, float2 xr, int tc) {
            float2 tp = *(const float2*)(tt + jc * TTS + 2 * lane);
            float cA = (m.x + xr.x) + tp.x;
            float cB = (m.y + xr.y) + tp.y;
            unsigned long long mA = __ballot(cA == target);
            unsigned long long mB = __ballot(cB == target);
            int iA = mA ? (2 * (__ffsll(mA) - 1))     : (1 << 30);
            int iB = mB ? (2 * (__ffsll(mB) - 1) + 1) : (1 << 30);
            int bp = (iA < iB) ? iA : iB;
            if (lane == 0) tagBuf[tc - 1] = bp;
            target = extract2(m, bp);        // M[t-1][bp] for the next step
            jc = bp;
        };

        // 8-deep prefetch ring, statically unrolled
        float2 m0 = wrow(L - 2), x0 = xrow(L - 2);
        float2 m1 = wrow(L - 3), x1 = xrow(L - 3);
        float2 m2 = wrow(L - 4), x2 = xrow(L - 4);
        float2 m3 = wrow(L - 5), x3 = xrow(L - 5);
        float2 m4 = wrow(L - 6), x4 = xrow(L - 6);
        float2 m5 = wrow(L - 7), x5 = xrow(L - 7);
        float2 m6 = wrow(L - 8), x6 = xrow(L - 8);
        float2 m7 = wrow(L - 9), x7 = xrow(L - 9);
        int tb = L - 1;
        while (tb >= 8) {
            chase(m0, x0, tb);     m0 = wrow(tb - 9);  x0 = xrow(tb - 9);
            chase(m1, x1, tb - 1); m1 = wrow(tb - 10); x1 = xrow(tb - 10);
            chase(m2, x2, tb - 2); m2 = wrow(tb - 11); x2 = xrow(tb - 11);
            chase(m3, x3, tb - 3); m3 = wrow(tb - 12); x3 = xrow(tb - 12);
            chase(m4, x4, tb - 4); m4 = wrow(tb - 13); x4 = xrow(tb - 13);
            chase(m5, x5, tb - 5); m5 = wrow(tb - 14); x5 = xrow(tb - 14);
            chase(m6, x6, tb - 6); m6 = wrow(tb - 15); x6 = xrow(tb - 15);
            chase(m7, x7, tb - 7); m7 = wrow(tb - 16); x7 = xrow(tb - 16);
            tb -= 8;
        }
        if (tb >= 1) chase(m0, x0, tb);
        if (tb >= 2) chase(m1, x1, tb - 1);
        if (tb >= 3) chase(m2, x2, tb - 2);
        if (tb >= 4) chase(m3, x3, tb - 3);
        if (tb >= 5) chase(m4, x4, tb - 4);
        if (tb >= 6) chase(m5, x5, tb - 5);
        if (tb >= 7) chase(m6, x6, tb - 6);
    }
    __syncthreads();

    // Coalesced output: tags for k < L, zeros for the masked tail.
    out[(size_t)b * TT + tid]       = (tid < L)       ? tagBuf[tid]       : 0;
    out[(size_t)b * TT + tid + 256] = (tid + 256 < L) ? tagBuf[tid + 256] : 0;
}

// ---------------- FALLBACK kernel: R5 (proven), used if ws too small --------
__global__ __launch_bounds__(FTHR, 1)
void crf_viterbi_fallback(const float* __restrict__ logits,
                          const float* __restrict__ trans,
                          const int* __restrict__ seqlen,
                          int* __restrict__ out) {
    __shared__ float stateBuf[2][SROW];
    __shared__ float redV[NN];
    __shared__ int   redI[NN];
    __shared__ int   tagBuf[TT];
    __shared__ int   entryTag[MAXG];
    __shared__ unsigned char bp[TT][NN];
    __shared__ unsigned char hist[MAXG][BD][NN];

    const int tid = threadIdx.x;
    const int j   = tid >> 3;
    const int c   = tid & 7;
    const int i0  = c << 4;
    const int b   = blockIdx.x;
    const int L   = seqlen[b];

    float tr0[16], tr1[16];
    #pragma unroll
    for (int k = 0; k < 16; ++k) {
        tr0[k] = trans[(i0 + k) * NN + j];
        tr1[k] = trans[(i0 + k) * NN + j + 64];
    }

    const float* lrow = logits + (size_t)b * TT * NN;
    if (c < 2) {
        int jj = j + (c << 6);
        stateBuf[0][SW(jj)] = lrow[jj];
    }
    __syncthreads();

    float xa0 = lrow[NN + j], xa1 = lrow[NN + j + 64];
    int p = 0;
    for (int t = 1; t < L; ++t) {
        int tn = (t + 1 < L) ? (t + 1) : (L - 1);
        const float* lp = lrow + tn * NN;
        float xb0 = lp[j];
        float xb1 = lp[j + 64];

        const float* st = stateBuf[p] + 20 * c;
        float4 a0 = *(const float4*)(st);
        float4 a1 = *(const float4*)(st + 4);
        float4 a2 = *(const float4*)(st + 8);
        float4 a3 = *(const float4*)(st + 12);

        float best0 = -__builtin_inff(), best1 = -__builtin_inff();
        int arg0 = 0, arg1 = 0;
        #define ELEM(S, K)                                                  \
        {                                                                   \
            float sc = (S) + tr0[K];                                        \
            bool g = sc > best0; best0 = g ? sc : best0; arg0 = g ? (K) : arg0; \
            float sd = (S) + tr1[K];                                        \
            bool h = sd > best1; best1 = h ? sd : best1; arg1 = h ? (K) : arg1; \
        }
        ELEM(a0.x, 0)  ELEM(a0.y, 1)  ELEM(a0.z, 2)  ELEM(a0.w, 3)
        ELEM(a1.x, 4)  ELEM(a1.y, 5)  ELEM(a1.z, 6)  ELEM(a1.w, 7)
        ELEM(a2.x, 8)  ELEM(a2.y, 9)  ELEM(a2.z, 10) ELEM(a2.w, 11)
        ELEM(a3.x, 12) ELEM(a3.y, 13) ELEM(a3.z, 14) ELEM(a3.w, 15)
        #undef ELEM

        float bv0 = best0, bv1 = best1;
        int   bi0 = i0 + arg0, bi1 = i0 + arg1;
        #define MERGE_STAGE(CTRL, LOWER)                                   \
        {                                                                  \
            float p0 = dpp_f<CTRL>(bv0); int q0 = dpp_i<CTRL>(bi0);        \
            float p1 = dpp_f<CTRL>(bv1); int q1 = dpp_i<CTRL>(bi1);        \
            bool lower = (LOWER);                                          \
            bool t0 = (p0 > bv0) || (p0 == bv0 && lower);                  \
            bool t1 = (p1 > bv1) || (p1 == bv1 && lower);                  \
            bv0 = t0 ? p0 : bv0; bi0 = t0 ? q0 : bi0;                      \
            bv1 = t1 ? p1 : bv1; bi1 = t1 ? q1 : bi1;                      \
        }
        MERGE_STAGE(DPP_XOR1, (c & 1) != 0)
        MERGE_STAGE(DPP_XOR2, (c & 2) != 0)
        MERGE_STAGE(DPP_MIR7, (c & 4) != 0)
        #undef MERGE_STAGE

        if (c < 2) {
            int   jj = j + (c << 6);
            float bv = c ? bv1 : bv0;
            int   bi = c ? bi1 : bi0;
            float xx = c ? xa1 : xa0;
            stateBuf[p ^ 1][SW(jj)] = bv + xx;
            bp[t][jj] = (unsigned char)bi;
        }
        xa0 = xb0; xa1 = xb1;
        __syncthreads();
        p ^= 1;
    }

    if (tid < NN) { redV[tid] = stateBuf[p][SW(tid)]; redI[tid] = tid; }
    __syncthreads();
    #pragma unroll
    for (int off = 64; off >= 1; off >>= 1) {
        if (tid < off) {
            float va = redV[tid], vb = redV[tid + off];
            int   ia = redI[tid], ib = redI[tid + off];
            if (vb > va || (vb == va && ib < ia)) { redV[tid] = vb; redI[tid] = ib; }
        }
        __syncthreads();
    }

    const int M = L - 1;
    const int G = (M + BD - 1) / BD;
    {
        int s  = tid & 127;
        int gA = tid >> 7;
        int gB = gA + 4;
        int thA = M - gA * BD, thB = M - gB * BD;
        int dA  = (gA < G) ? ((thA < BD) ? thA : BD) : 0;
        int dB  = (gB < G) ? ((thB < BD) ? thB : BD) : 0;
        int curA = s, curB = s;
        int maxd = (dA > dB) ? dA : dB;
        for (int d = 0; d < maxd; ++d) {
            if (d < dA) { curA = bp[thA - d][curA]; hist[gA][d][s] = (unsigned char)curA; }
            if (d < dB) { curB = bp[thB - d][curB]; hist[gB][d][s] = (unsigned char)curB; }
        }
    }
    __syncthreads();
    if (tid == 0) {
        int e = redI[0];
        tagBuf[L - 1] = e;
        for (int g = 0; g < G; ++g) {
            entryTag[g] = e;
            if (g + 1 < G) e = hist[g][BD - 1][e];
        }
    }
    __syncthreads();
    {
        int g = tid >> 6, d = tid & 63;
        if (g < MAXG && g < G) {
            int th  = M - g * BD;
            int dep = (th < BD) ? th : BD;
            if (d < dep) {
                int e = entryTag[g];
                tagBuf[th - 1 - d] = hist[g][d][e];
            }
        }
    }
    __syncthreads();
    out[(size_t)b * TT + tid] = (tid < L) ? tagBuf[tid] : 0;
}

extern "C" void kernel_launch(void* const* d_in, const int* in_sizes, int n_in,
                              void* d_out, int out_size, void* d_ws, size_t ws_size,
                              hipStream_t stream) {
    const float* logits = (const float*)d_in[0];
    const float* trans  = (const float*)d_in[1];
    const int*   seqlen = (const int*)d_in[2];
    int*         out    = (int*)d_out;
    const int B = in_sizes[2];  // 256
    const size_t need = (size_t)B * TT * NN * sizeof(float);  // 64 MiB
    if (ws_size >= need) {
        crf_viterbi_fast<<<B, NTHR, 0, stream>>>(logits, trans, seqlen, out,
                                                 (float*)d_ws);
    } else {
        crf_viterbi_fallback<<<B, FTHR, 0, stream>>>(logits, trans, seqlen, out);
    }
}